// Round 1
// 2391.076 us; speedup vs baseline: 1.0489x; 1.0489x over previous
//
#include <hip/hip_runtime.h>

#define BB 64
#define SS 1024
#define II 128
#define HH 256
#define OO 128

#if __has_builtin(__builtin_amdgcn_fdot2)
#define HAVE_DOT2 1
#endif

typedef __fp16 h2_t __attribute__((ext_vector_type(2)));

__device__ __forceinline__ float blo(unsigned u) { return __uint_as_float(u << 16); }
__device__ __forceinline__ float bhi(unsigned u) { return __uint_as_float(u & 0xffff0000u); }

__device__ __forceinline__ unsigned pack_bf2(float a, float b) {
    unsigned ua = __float_as_uint(a);
    unsigned ub = __float_as_uint(b);
    ua = (ua + 0x7fffu + ((ua >> 16) & 1u)) >> 16;
    ub = (ub + 0x7fffu + ((ub >> 16) & 1u)) & 0xffff0000u;
    return ua | ub;
}

__device__ __forceinline__ unsigned packh(float a, float b) {
#ifdef HAVE_DOT2
    union { h2_t h; unsigned u; } cv;
    cv.h = __builtin_amdgcn_cvt_pkrtz(a, b);   // v_cvt_pkrtz_f16_f32
    return cv.u;
#else
    return pack_bf2(a, b);
#endif
}

__device__ __forceinline__ float dot2acc(unsigned w, unsigned h, float acc) {
#ifdef HAVE_DOT2
    union { unsigned u; h2_t h; } cw, ch;
    cw.u = w; ch.u = h;
    return __builtin_amdgcn_fdot2(cw.h, ch.h, acc, false);
#else
    return fmaf(blo(w), blo(h), fmaf(bhi(w), bhi(h), acc));
#endif
}

// ---------------------------------------------------------------------------
// Kernel A: inp[b,t,h] = x[b,t,:] @ W_in[h,:] + b_in[h]  -> states region
// ---------------------------------------------------------------------------
__global__ __launch_bounds__(256)
void ltc_inproj(const float* __restrict__ x, const float* __restrict__ W_in,
                const float* __restrict__ b_in, float* __restrict__ inp)
{
    __shared__ float smem[64 * 130];
    const int t = threadIdx.x;
    const int l = t & 63, w = t >> 6;
    const int r0 = blockIdx.x * 64;

    float2* xs2 = (float2*)smem;                // [64][65] float2
    for (int idx = t; idx < 64 * 64; idx += 256) {
        int row = idx >> 6, c2 = idx & 63;
        xs2[row * 65 + c2] = ((const float2*)x)[(size_t)(r0 + row) * 64 + c2];
    }
    __syncthreads();
    float xr[128];
#pragma unroll
    for (int i = 0; i < 64; ++i) {
        float2 v = xs2[l * 65 + i];
        xr[2 * i] = v.x; xr[2 * i + 1] = v.y;
    }
    __syncthreads();

    for (int ph = 0; ph < 2; ++ph) {
        for (int i = 0; i < 32; ++i) {
            const int hh = 128 * ph + 32 * w + i;
            const float4* wr = (const float4*)(W_in + (size_t)hh * II);
            float a0 = b_in[hh], a1 = 0.f, a2 = 0.f, a3 = 0.f;
#pragma unroll
            for (int j = 0; j < 32; ++j) {
                float4 wv = wr[j];
                a0 = fmaf(wv.x, xr[4 * j + 0], a0);
                a1 = fmaf(wv.y, xr[4 * j + 1], a1);
                a2 = fmaf(wv.z, xr[4 * j + 2], a2);
                a3 = fmaf(wv.w, xr[4 * j + 3], a3);
            }
            smem[l * 128 + ((32 * w + i + l) & 127)] = a0 + a1 + a2 + a3;
        }
        __syncthreads();
        for (int k = 0; k < 32; ++k) {
            int idx = k * 256 + t;
            int row = idx >> 7, c = idx & 127;
            inp[(size_t)(r0 + row) * HH + 128 * ph + c] = smem[row * 128 + ((c + row) & 127)];
        }
        __syncthreads();
    }
}

// ---------------------------------------------------------------------------
// Kernel B: persistent recurrence. 64 blocks x 512 thr (2 waves/SIMD).
// NEW layout: thread t -> (r = t>>1, half = t&1). The two half-row partials
// for row r live in ADJACENT LANES of the same wave:
//   - cross-half reduction = __shfl_xor(.,1)  (no LDS partials, no barrier)
//   - pointwise runs redundantly on both lanes (bit-identical: only operand
//     commutativity differs, so the two h copies stay in lockstep)
//   - h packed-f16 pairs built via __shfl_xor(.,2), written by t%4==0 threads
//   - h_p DOUBLE-BUFFERED in LDS -> exactly ONE __syncthreads per step
// __launch_bounds__(512,2): min 2 waves/EU caps VGPRs at 256 so the 192
// packed-weight dwords stay in arch VGPRs (round-0 counters showed
// VGPR_Count=128 => weights had been demoted to AGPRs, doubling dot VALU).
// ---------------------------------------------------------------------------
__global__ __launch_bounds__(512, 2)
void ltc_recurrent(const float* __restrict__ W_rec, const float* __restrict__ b_rec,
                   const float* __restrict__ W_cg,  const float* __restrict__ b_cg,
                   const float* __restrict__ W_eg,  const float* __restrict__ b_eg,
                   const float* __restrict__ tau,
                   float* __restrict__ st)          // [B,S,H]: inp staged in, states out
{
    const int b = blockIdx.x, t = threadIdx.x;
    const int r = t >> 1, half = t & 1;

    __shared__ __align__(16) unsigned h_p[2][HH / 2];   // double-buffered packed h

    unsigned wR[64], wC[64], wE[64];
    {
        const float4* R4 = (const float4*)(W_rec + (size_t)r * HH + half * 128);
        const float4* C4 = (const float4*)(W_cg  + (size_t)r * HH + half * 128);
        const float4* E4 = (const float4*)(W_eg  + (size_t)r * HH + half * 128);
#pragma unroll
        for (int j = 0; j < 32; ++j) {
            float4 v = R4[j]; wR[2 * j] = packh(v.x, v.y); wR[2 * j + 1] = packh(v.z, v.w);
        }
#pragma unroll
        for (int j = 0; j < 32; ++j) {
            float4 v = C4[j]; wC[2 * j] = packh(v.x, v.y); wC[2 * j + 1] = packh(v.z, v.w);
        }
#pragma unroll
        for (int j = 0; j < 32; ++j) {
            float4 v = E4[j]; wE[2 * j] = packh(v.x, v.y); wE[2 * j + 1] = packh(v.z, v.w);
        }
    }

    // pointwise constants for row r (held redundantly by both half-lanes)
    const float ti = 1.0f / tau[r];
    const float bR = b_rec[r], bC = b_cg[r], bE = b_eg[r];

    float* stb = st + (size_t)b * SS * HH;
    float hr = 0.f;                    // f32 state for row r
    float inpC = stb[r];               // inp(0, r)

    if (t < 128) h_p[0][t] = 0u;
    __syncthreads();

    for (int s = 0; s < SS; ++s) {
        float inpN = 0.f;
        if (s + 1 < SS) inpN = stb[(size_t)(s + 1) * HH + r];

        const uint4* hp4 = (const uint4*)(h_p[s & 1]) + half * 16;  // this half's 16 uint4
        float aR0 = 0.f, aR1 = 0.f, aC0 = 0.f, aC1 = 0.f, aE0 = 0.f, aE1 = 0.f;
#pragma unroll
        for (int c = 0; c < 4; ++c) {                   // 4 chunks x 16 packed dwords
            uint4 q0 = hp4[c * 4 + 0], q1 = hp4[c * 4 + 1];
            uint4 q2 = hp4[c * 4 + 2], q3 = hp4[c * 4 + 3];
            unsigned hw[16] = {q0.x, q0.y, q0.z, q0.w, q1.x, q1.y, q1.z, q1.w,
                               q2.x, q2.y, q2.z, q2.w, q3.x, q3.y, q3.z, q3.w};
#pragma unroll
            for (int j = 0; j < 16; j += 2) {
                aR0 = dot2acc(wR[c * 16 + j],     hw[j],     aR0);
                aC0 = dot2acc(wC[c * 16 + j],     hw[j],     aC0);
                aE0 = dot2acc(wE[c * 16 + j],     hw[j],     aE0);
                aR1 = dot2acc(wR[c * 16 + j + 1], hw[j + 1], aR1);
                aC1 = dot2acc(wC[c * 16 + j + 1], hw[j + 1], aC1);
                aE1 = dot2acc(wE[c * 16 + j + 1], hw[j + 1], aE1);
            }
        }
        float aR = aR0 + aR1, aC = aC0 + aC1, aE = aE0 + aE1;
        aR += __shfl_xor(aR, 1);                         // cross-half reduce in-wave
        aC += __shfl_xor(aC, 1);
        aE += __shfl_xor(aE, 1);

        // pointwise for row r (both half-lanes compute identical values)
        float rec = aR + bR;
        float cm = 1.0f / (1.0f + expf(-(aC + bC)));
        float em = tanhf(aE + bE);
        float p  = inpC + rec;
        float rl = p > 0.f ? p : 0.f;
        float dh = (rl - hr) * ti * cm + 0.1f * em;
        hr = fmaf(0.1f, dh, hr);

        // pack rows (r, r+1): t%4==0 threads (r even, half 0) grab neighbor h
        float hnb = __shfl_xor(hr, 2);
        if ((t & 3) == 0) {
            h_p[(s + 1) & 1][r >> 1] = packh(hr, hnb);
            float2 hv; hv.x = hr; hv.y = hnb;
            ((float2*)(stb + (size_t)s * HH))[r >> 1] = hv;
        }
        inpC = inpN;
        __syncthreads();                                 // h_p[(s+1)&1] visible
    }
}

// ---------------------------------------------------------------------------
// Kernel C: outputs[row,o] = b_out[o] + states[row,:] @ W_out[o,:]
// Two K-phases of 128 with 32 per-thread accumulators (no 256-dword array,
// no spill). Lane = row, W_out rows broadcast, LDS-swizzled coalesced store.
// ---------------------------------------------------------------------------
__global__ __launch_bounds__(256)
void ltc_out(const float* __restrict__ states, const float* __restrict__ W_out,
             const float* __restrict__ b_out, float* __restrict__ outputs)
{
    __shared__ float smem[64 * 130];
    const int t = threadIdx.x;
    const int l = t & 63, w = t >> 6;
    const int r0 = blockIdx.x * 64;

    float osacc[32];
#pragma unroll
    for (int i = 0; i < 32; ++i) osacc[i] = b_out[32 * w + i];

    float2* xs2 = (float2*)smem;                // [64][65] float2
    for (int ph = 0; ph < 2; ++ph) {
        for (int idx = t; idx < 64 * 64; idx += 256) {
            int row = idx >> 6, c2 = idx & 63;
            xs2[row * 65 + c2] = ((const float2*)states)[(size_t)(r0 + row) * 128 + ph * 64 + c2];
        }
        __syncthreads();
        float xr[128];
#pragma unroll
        for (int i = 0; i < 64; ++i) {
            float2 v = xs2[l * 65 + i];
            xr[2 * i] = v.x; xr[2 * i + 1] = v.y;
        }
        __syncthreads();                        // xs consumed; safe to restage next ph

        for (int i = 0; i < 32; ++i) {
            const int oo = 32 * w + i;
            const float4* wr = (const float4*)(W_out + (size_t)oo * HH + ph * 128);
            float a0 = 0.f, a1 = 0.f, a2 = 0.f, a3 = 0.f;
#pragma unroll
            for (int j = 0; j < 32; ++j) {
                float4 wv = wr[j];
                a0 = fmaf(wv.x, xr[4 * j + 0], a0);
                a1 = fmaf(wv.y, xr[4 * j + 1], a1);
                a2 = fmaf(wv.z, xr[4 * j + 2], a2);
                a3 = fmaf(wv.w, xr[4 * j + 3], a3);
            }
            osacc[i] += (a0 + a1) + (a2 + a3);
        }
    }

    __syncthreads();                            // smem free for output staging
#pragma unroll
    for (int i = 0; i < 32; ++i)
        smem[l * 128 + ((32 * w + i + l) & 127)] = osacc[i];
    __syncthreads();
    for (int k = 0; k < 32; ++k) {
        int idx = k * 256 + t;
        int row = idx >> 7, c = idx & 127;
        outputs[(size_t)(r0 + row) * OO + c] = smem[row * 128 + ((c + row) & 127)];
    }
}

extern "C" void kernel_launch(void* const* d_in, const int* in_sizes, int n_in,
                              void* d_out, int out_size, void* d_ws, size_t ws_size,
                              hipStream_t stream) {
    const float* x      = (const float*)d_in[0];
    const float* W_in   = (const float*)d_in[1];
    const float* b_in   = (const float*)d_in[2];
    const float* W_rec  = (const float*)d_in[3];
    const float* b_rec  = (const float*)d_in[4];
    const float* W_out  = (const float*)d_in[5];
    const float* b_out  = (const float*)d_in[6];
    const float* W_cg   = (const float*)d_in[7];
    const float* b_cg   = (const float*)d_in[8];
    const float* W_eg   = (const float*)d_in[9];
    const float* b_eg   = (const float*)d_in[10];
    const float* tau    = (const float*)d_in[11];

    float* outputs = (float*)d_out;                       // [B,S,O]
    float* states  = outputs + (size_t)BB * SS * OO;      // [B,S,H] (inp staging -> states)

    hipLaunchKernelGGL(ltc_inproj, dim3(BB * SS / 64), dim3(256), 0, stream,
                       x, W_in, b_in, states);
    hipLaunchKernelGGL(ltc_recurrent, dim3(BB), dim3(512), 0, stream,
                       W_rec, b_rec, W_cg, b_cg, W_eg, b_eg, tau, states);
    hipLaunchKernelGGL(ltc_out, dim3(BB * SS / 64), dim3(256), 0, stream,
                       states, W_out, b_out, outputs);
}

// Round 2
// 2222.868 us; speedup vs baseline: 1.1282x; 1.0757x over previous
//
#include <hip/hip_runtime.h>

#define BB 64
#define SS 1024
#define II 128
#define HH 256
#define OO 128

#if __has_builtin(__builtin_amdgcn_fdot2)
#define HAVE_DOT2 1
#endif

typedef __fp16 h2_t __attribute__((ext_vector_type(2)));

__device__ __forceinline__ float blo(unsigned u) { return __uint_as_float(u << 16); }
__device__ __forceinline__ float bhi(unsigned u) { return __uint_as_float(u & 0xffff0000u); }

__device__ __forceinline__ unsigned pack_bf2(float a, float b) {
    unsigned ua = __float_as_uint(a);
    unsigned ub = __float_as_uint(b);
    ua = (ua + 0x7fffu + ((ua >> 16) & 1u)) >> 16;
    ub = (ub + 0x7fffu + ((ub >> 16) & 1u)) & 0xffff0000u;
    return ua | ub;
}

__device__ __forceinline__ unsigned packh(float a, float b) {
#ifdef HAVE_DOT2
    union { h2_t h; unsigned u; } cv;
    cv.h = __builtin_amdgcn_cvt_pkrtz(a, b);   // v_cvt_pkrtz_f16_f32
    return cv.u;
#else
    return pack_bf2(a, b);
#endif
}

__device__ __forceinline__ float dot2acc(unsigned w, unsigned h, float acc) {
#ifdef HAVE_DOT2
    union { unsigned u; h2_t h; } cw, ch;
    cw.u = w; ch.u = h;
    return __builtin_amdgcn_fdot2(cw.h, ch.h, acc, false);
#else
    return fmaf(blo(w), blo(h), fmaf(bhi(w), bhi(h), acc));
#endif
}

// fast transcendentals: error ~1e-6, far below the f16-weight noise floor.
// Saturation: exp2(+inf)->inf, rcp(inf)->0 => sigmoid->{0,1}, tanh->{-1,1}. OK.
__device__ __forceinline__ float fsigmoid(float x) {
    float e = __builtin_amdgcn_exp2f(-1.4426950408889634f * x);
    return __builtin_amdgcn_rcpf(1.0f + e);
}
__device__ __forceinline__ float ftanh(float x) {
    float e = __builtin_amdgcn_exp2f(2.8853900817779268f * x);   // e^(2x)
    return 1.0f - 2.0f * __builtin_amdgcn_rcpf(1.0f + e);
}

// barrier that does NOT drain vmcnt: __syncthreads() emits
// s_waitcnt vmcnt(0) lgkmcnt(0) + s_barrier, which serializes the per-step
// global store (state write) and load (inp prefetch) onto the critical path.
// Only the ds_write needs to be visible -> lgkmcnt(0) suffices.
__device__ __forceinline__ void bar_lds() {
    asm volatile("s_waitcnt lgkmcnt(0)\n\ts_barrier" ::: "memory");
}

// ---------------------------------------------------------------------------
// Kernel A: inp[b,t,h] = x[b,t,:] @ W_in[h,:] + b_in[h]  -> states region
// ---------------------------------------------------------------------------
__global__ __launch_bounds__(256)
void ltc_inproj(const float* __restrict__ x, const float* __restrict__ W_in,
                const float* __restrict__ b_in, float* __restrict__ inp)
{
    __shared__ float smem[64 * 130];
    const int t = threadIdx.x;
    const int l = t & 63, w = t >> 6;
    const int r0 = blockIdx.x * 64;

    float2* xs2 = (float2*)smem;                // [64][65] float2
    for (int idx = t; idx < 64 * 64; idx += 256) {
        int row = idx >> 6, c2 = idx & 63;
        xs2[row * 65 + c2] = ((const float2*)x)[(size_t)(r0 + row) * 64 + c2];
    }
    __syncthreads();
    float xr[128];
#pragma unroll
    for (int i = 0; i < 64; ++i) {
        float2 v = xs2[l * 65 + i];
        xr[2 * i] = v.x; xr[2 * i + 1] = v.y;
    }
    __syncthreads();

    for (int ph = 0; ph < 2; ++ph) {
        for (int i = 0; i < 32; ++i) {
            const int hh = 128 * ph + 32 * w + i;
            const float4* wr = (const float4*)(W_in + (size_t)hh * II);
            float a0 = b_in[hh], a1 = 0.f, a2 = 0.f, a3 = 0.f;
#pragma unroll
            for (int j = 0; j < 32; ++j) {
                float4 wv = wr[j];
                a0 = fmaf(wv.x, xr[4 * j + 0], a0);
                a1 = fmaf(wv.y, xr[4 * j + 1], a1);
                a2 = fmaf(wv.z, xr[4 * j + 2], a2);
                a3 = fmaf(wv.w, xr[4 * j + 3], a3);
            }
            smem[l * 128 + ((32 * w + i + l) & 127)] = a0 + a1 + a2 + a3;
        }
        __syncthreads();
        for (int k = 0; k < 32; ++k) {
            int idx = k * 256 + t;
            int row = idx >> 7, c = idx & 127;
            inp[(size_t)(r0 + row) * HH + 128 * ph + c] = smem[row * 128 + ((c + row) & 127)];
        }
        __syncthreads();
    }
}

// ---------------------------------------------------------------------------
// Kernel B: persistent recurrence. 64 blocks x 512 thr (2 waves/SIMD).
// Thread t -> (r = t>>1, half = t&1): cross-half reduce = __shfl_xor(.,1),
// pointwise redundant on both lanes (lockstep). h_p double-buffered in LDS,
// ONE lgkmcnt-only barrier per step (no vmcnt drain: per-step global store
// and inp prefetch stay in flight across the barrier).
// Odd half padded +4 dwords so even/odd lanes hit disjoint bank groups.
// ---------------------------------------------------------------------------
__global__ __launch_bounds__(512)
void ltc_recurrent(const float* __restrict__ W_rec, const float* __restrict__ b_rec,
                   const float* __restrict__ W_cg,  const float* __restrict__ b_cg,
                   const float* __restrict__ W_eg,  const float* __restrict__ b_eg,
                   const float* __restrict__ tau,
                   float* __restrict__ st)          // [B,S,H]: inp staged in, states out
{
    const int b = blockIdx.x, t = threadIdx.x;
    const int r = t >> 1, half = t & 1;

    // [buf][132]: dwords 0..63 = packed pairs 0..63, pad 64..67, 68..131 = pairs 64..127
    __shared__ __align__(16) unsigned h_p[2][132];

    unsigned wR[64], wC[64], wE[64];
    {
        const float4* R4 = (const float4*)(W_rec + (size_t)r * HH + half * 128);
        const float4* C4 = (const float4*)(W_cg  + (size_t)r * HH + half * 128);
        const float4* E4 = (const float4*)(W_eg  + (size_t)r * HH + half * 128);
#pragma unroll
        for (int j = 0; j < 32; ++j) {
            float4 v = R4[j]; wR[2 * j] = packh(v.x, v.y); wR[2 * j + 1] = packh(v.z, v.w);
        }
#pragma unroll
        for (int j = 0; j < 32; ++j) {
            float4 v = C4[j]; wC[2 * j] = packh(v.x, v.y); wC[2 * j + 1] = packh(v.z, v.w);
        }
#pragma unroll
        for (int j = 0; j < 32; ++j) {
            float4 v = E4[j]; wE[2 * j] = packh(v.x, v.y); wE[2 * j + 1] = packh(v.z, v.w);
        }
    }

    // pointwise constants for row r (held redundantly by both half-lanes)
    const float ti = 1.0f / tau[r];
    const float bR = b_rec[r], bC = b_cg[r], bE = b_eg[r];

    float* stb = st + (size_t)b * SS * HH;
    float hr = 0.f;                    // f32 state for row r
    float inpC = stb[r];               // inp(0, r)

    if (t < 132) h_p[0][t] = 0u;
    bar_lds();

    for (int s = 0; s < SS; ++s) {
        float inpN = 0.f;
        if (s + 1 < SS) inpN = stb[(size_t)(s + 1) * HH + r];

        const uint4* hp4 = (const uint4*)(h_p[s & 1]) + half * 17;  // 17 uint4 = 68 dwords
        float aR0 = 0.f, aR1 = 0.f, aC0 = 0.f, aC1 = 0.f, aE0 = 0.f, aE1 = 0.f;
#pragma unroll
        for (int c = 0; c < 4; ++c) {                   // 4 chunks x 16 packed dwords
            uint4 q0 = hp4[c * 4 + 0], q1 = hp4[c * 4 + 1];
            uint4 q2 = hp4[c * 4 + 2], q3 = hp4[c * 4 + 3];
#define DOTQ(Q, k0, k1, k2, k3) \
            aR0 = dot2acc(wR[c * 16 + k0], Q.x, aR0); \
            aC0 = dot2acc(wC[c * 16 + k0], Q.x, aC0); \
            aE0 = dot2acc(wE[c * 16 + k0], Q.x, aE0); \
            aR1 = dot2acc(wR[c * 16 + k1], Q.y, aR1); \
            aC1 = dot2acc(wC[c * 16 + k1], Q.y, aC1); \
            aE1 = dot2acc(wE[c * 16 + k1], Q.y, aE1); \
            aR0 = dot2acc(wR[c * 16 + k2], Q.z, aR0); \
            aC0 = dot2acc(wC[c * 16 + k2], Q.z, aC0); \
            aE0 = dot2acc(wE[c * 16 + k2], Q.z, aE0); \
            aR1 = dot2acc(wR[c * 16 + k3], Q.w, aR1); \
            aC1 = dot2acc(wC[c * 16 + k3], Q.w, aC1); \
            aE1 = dot2acc(wE[c * 16 + k3], Q.w, aE1);
            DOTQ(q0, 0, 1, 2, 3)
            DOTQ(q1, 4, 5, 6, 7)
            DOTQ(q2, 8, 9, 10, 11)
            DOTQ(q3, 12, 13, 14, 15)
#undef DOTQ
        }
        float aR = aR0 + aR1, aC = aC0 + aC1, aE = aE0 + aE1;
        aR += __shfl_xor(aR, 1);                         // cross-half reduce in-wave
        aC += __shfl_xor(aC, 1);
        aE += __shfl_xor(aE, 1);

        // pointwise for row r (both half-lanes compute identical values)
        float rec = aR + bR;
        float cm = fsigmoid(aC + bC);
        float em = ftanh(aE + bE);
        float p  = inpC + rec;
        float rl = p > 0.f ? p : 0.f;
        float dh = (rl - hr) * ti * cm + 0.1f * em;
        hr = fmaf(0.1f, dh, hr);

        // pack rows (r, r+1): t%4==0 threads (r even, half 0) grab neighbor h
        float hnb = __shfl_xor(hr, 2);
        if ((t & 3) == 0) {
            int wi = t >> 2;                             // pair index 0..127
            int wo = wi + ((wi >> 6) << 2);              // +4 pad for pairs >= 64
            h_p[(s + 1) & 1][wo] = packh(hr, hnb);
            float2 hv; hv.x = hr; hv.y = hnb;
            ((float2*)(stb + (size_t)s * HH))[wi] = hv;
        }
        inpC = inpN;
        bar_lds();                                       // h_p[(s+1)&1] visible
    }
}

// ---------------------------------------------------------------------------
// Kernel C: outputs[row,o] = b_out[o] + states[row,:] @ W_out[o,:]
// Two K-phases of 128 with 32 per-thread accumulators (no 256-dword array,
// no spill). Lane = row, W_out rows broadcast, LDS-swizzled coalesced store.
// ---------------------------------------------------------------------------
__global__ __launch_bounds__(256)
void ltc_out(const float* __restrict__ states, const float* __restrict__ W_out,
             const float* __restrict__ b_out, float* __restrict__ outputs)
{
    __shared__ float smem[64 * 130];
    const int t = threadIdx.x;
    const int l = t & 63, w = t >> 6;
    const int r0 = blockIdx.x * 64;

    float osacc[32];
#pragma unroll
    for (int i = 0; i < 32; ++i) osacc[i] = b_out[32 * w + i];

    float2* xs2 = (float2*)smem;                // [64][65] float2
    for (int ph = 0; ph < 2; ++ph) {
        for (int idx = t; idx < 64 * 64; idx += 256) {
            int row = idx >> 6, c2 = idx & 63;
            xs2[row * 65 + c2] = ((const float2*)states)[(size_t)(r0 + row) * 128 + ph * 64 + c2];
        }
        __syncthreads();
        float xr[128];
#pragma unroll
        for (int i = 0; i < 64; ++i) {
            float2 v = xs2[l * 65 + i];
            xr[2 * i] = v.x; xr[2 * i + 1] = v.y;
        }
        __syncthreads();                        // xs consumed; safe to restage next ph

        for (int i = 0; i < 32; ++i) {
            const int oo = 32 * w + i;
            const float4* wr = (const float4*)(W_out + (size_t)oo * HH + ph * 128);
            float a0 = 0.f, a1 = 0.f, a2 = 0.f, a3 = 0.f;
#pragma unroll
            for (int j = 0; j < 32; ++j) {
                float4 wv = wr[j];
                a0 = fmaf(wv.x, xr[4 * j + 0], a0);
                a1 = fmaf(wv.y, xr[4 * j + 1], a1);
                a2 = fmaf(wv.z, xr[4 * j + 2], a2);
                a3 = fmaf(wv.w, xr[4 * j + 3], a3);
            }
            osacc[i] += (a0 + a1) + (a2 + a3);
        }
    }

    __syncthreads();                            // smem free for output staging
#pragma unroll
    for (int i = 0; i < 32; ++i)
        smem[l * 128 + ((32 * w + i + l) & 127)] = osacc[i];
    __syncthreads();
    for (int k = 0; k < 32; ++k) {
        int idx = k * 256 + t;
        int row = idx >> 7, c = idx & 127;
        outputs[(size_t)(r0 + row) * OO + c] = smem[row * 128 + ((c + row) & 127)];
    }
}

extern "C" void kernel_launch(void* const* d_in, const int* in_sizes, int n_in,
                              void* d_out, int out_size, void* d_ws, size_t ws_size,
                              hipStream_t stream) {
    const float* x      = (const float*)d_in[0];
    const float* W_in   = (const float*)d_in[1];
    const float* b_in   = (const float*)d_in[2];
    const float* W_rec  = (const float*)d_in[3];
    const float* b_rec  = (const float*)d_in[4];
    const float* W_out  = (const float*)d_in[5];
    const float* b_out  = (const float*)d_in[6];
    const float* W_cg   = (const float*)d_in[7];
    const float* b_cg   = (const float*)d_in[8];
    const float* W_eg   = (const float*)d_in[9];
    const float* b_eg   = (const float*)d_in[10];
    const float* tau    = (const float*)d_in[11];

    float* outputs = (float*)d_out;                       // [B,S,O]
    float* states  = outputs + (size_t)BB * SS * OO;      // [B,S,H] (inp staging -> states)

    hipLaunchKernelGGL(ltc_inproj, dim3(BB * SS / 64), dim3(256), 0, stream,
                       x, W_in, b_in, states);
    hipLaunchKernelGGL(ltc_recurrent, dim3(BB), dim3(512), 0, stream,
                       W_rec, b_rec, W_cg, b_cg, W_eg, b_eg, tau, states);
    hipLaunchKernelGGL(ltc_out, dim3(BB * SS / 64), dim3(256), 0, stream,
                       states, W_out, b_out, outputs);
}